// Round 1
// baseline (245.007 us; speedup 1.0000x reference)
//
#include <hip/hip_runtime.h>

#define CIN   256
#define COUT  32
#define IMG_H 96
#define IMG_W 96
#define HW    (IMG_H*IMG_W)
#define NB    2
#define NV    4
#define VSZ   64
#define NVOX  (VSZ*VSZ*VSZ)

// Kernel 1: 1x1 conv, output channel-last [b,v,h,w,c] for fast 128B gathers.
__global__ __launch_bounds__(256) void conv1x1_kernel(
    const float* __restrict__ features,   // [B,V,CIN,H,W]
    const float* __restrict__ Wp,         // [COUT,CIN]
    const float* __restrict__ bp,         // [COUT]
    float* __restrict__ out)              // [B,V,H,W,COUT]
{
    __shared__ float Wt[CIN*COUT];        // [c][o], 32 KiB
    const int tid = threadIdx.x;
    #pragma unroll
    for (int i = 0; i < CIN*COUT/256; ++i) {
        int idx = i*256 + tid;
        int c = idx >> 5, o = idx & 31;
        Wt[idx] = Wp[o*CIN + c];
    }
    __syncthreads();

    const int bv = blockIdx.y;
    const int hw = blockIdx.x*256 + tid;
    const float* f = features + (size_t)bv*CIN*HW + hw;

    float acc[COUT];
    #pragma unroll
    for (int o = 0; o < COUT; ++o) acc[o] = bp[o];   // uniform -> scalar loads

    #pragma unroll 4
    for (int c = 0; c < CIN; ++c) {
        float x = f[(size_t)c*HW];                    // coalesced across lanes
        const float4* wrow = (const float4*)(&Wt[c*COUT]);
        #pragma unroll
        for (int i = 0; i < 8; ++i) {
            float4 w4 = wrow[i];                      // ds_read_b128, broadcast
            acc[4*i+0] += x*w4.x; acc[4*i+1] += x*w4.y;
            acc[4*i+2] += x*w4.z; acc[4*i+3] += x*w4.w;
        }
    }

    float4* op = (float4*)(out + ((size_t)bv*HW + hw)*COUT);
    #pragma unroll
    for (int i = 0; i < 8; ++i)
        op[i] = make_float4(acc[4*i], acc[4*i+1], acc[4*i+2], acc[4*i+3]);
}

// Kernel 2: project voxel -> bilinear-sample 32 channels per view ->
// streaming softmax-weighted sum over views (no max-sub needed: |s| < ~10).
__global__ __launch_bounds__(256) void volgen_kernel(
    const float* __restrict__ feats,   // [B,V,H,W,COUT] channel-last
    const float* __restrict__ proj,    // [B,V,3,4]
    const float* __restrict__ coords,  // [B,NVOX,3]
    float* __restrict__ out)           // [B,COUT,NVOX]
{
    const int n = blockIdx.x*256 + threadIdx.x;
    const int b = blockIdx.y;                 // uniform per block -> scalar proj loads
    const float* cp = coords + ((size_t)b*NVOX + n)*3;
    const float X = cp[0], Y = cp[1], Z = cp[2];

    float A[COUT], Bs[COUT];
    #pragma unroll
    for (int c = 0; c < COUT; ++c) { A[c] = 0.f; Bs[c] = 0.f; }

    for (int v = 0; v < NV; ++v) {
        const float* P = proj + (size_t)(b*NV + v)*12;
        const float wz = P[8]*X + P[9]*Y + P[10]*Z + P[11];

        float4 s4[8];
        #pragma unroll
        for (int i = 0; i < 8; ++i) s4[i] = make_float4(0.f, 0.f, 0.f, 0.f);
        bool did = false;

        if (wz > 0.0f) {
            const float rz = __builtin_amdgcn_rcpf(wz);
            const float u  = (P[0]*X + P[1]*Y + P[2]*Z + P[3]) * rz;
            const float ve = (P[4]*X + P[5]*Y + P[6]*Z + P[7]) * rz;
            // gx=2(u/H-0.5); px=(gx+1)*0.5*(W-1)  ->  px = u*(W-1)/H  (H==W==96)
            const float px = u  * ((float)(IMG_W-1)/(float)IMG_H);
            const float py = ve * ((float)(IMG_H-1)/(float)IMG_W);
            const float fx0 = floorf(px), fy0 = floorf(py);
            const int x0 = (int)fx0, y0 = (int)fy0;
            const int x1 = x0 + 1,  y1 = y0 + 1;
            const bool vx0 = (x0 >= 0) & (x0 < IMG_W);
            const bool vx1 = (x1 >= 0) & (x1 < IMG_W);
            const bool vy0 = (y0 >= 0) & (y0 < IMG_H);
            const bool vy1 = (y1 >= 0) & (y1 < IMG_H);
            if ((vx0 | vx1) & (vy0 | vy1)) {          // at least one valid corner
                did = true;
                const float wx1 = px - fx0, wx0 = 1.f - wx1;
                const float wy1 = py - fy0, wy0 = 1.f - wy1;
                const float* base = feats + (size_t)(b*NV + v)*HW*COUT;
                if (vx0 & vy0) {
                    const float4* p = (const float4*)(base + (y0*IMG_W + x0)*COUT);
                    const float w = wx0*wy0;
                    #pragma unroll
                    for (int i = 0; i < 8; ++i) { float4 t = p[i];
                        s4[i].x += w*t.x; s4[i].y += w*t.y; s4[i].z += w*t.z; s4[i].w += w*t.w; }
                }
                if (vx1 & vy0) {
                    const float4* p = (const float4*)(base + (y0*IMG_W + x1)*COUT);
                    const float w = wx1*wy0;
                    #pragma unroll
                    for (int i = 0; i < 8; ++i) { float4 t = p[i];
                        s4[i].x += w*t.x; s4[i].y += w*t.y; s4[i].z += w*t.z; s4[i].w += w*t.w; }
                }
                if (vx0 & vy1) {
                    const float4* p = (const float4*)(base + (y1*IMG_W + x0)*COUT);
                    const float w = wx0*wy1;
                    #pragma unroll
                    for (int i = 0; i < 8; ++i) { float4 t = p[i];
                        s4[i].x += w*t.x; s4[i].y += w*t.y; s4[i].z += w*t.z; s4[i].w += w*t.w; }
                }
                if (vx1 & vy1) {
                    const float4* p = (const float4*)(base + (y1*IMG_W + x1)*COUT);
                    const float w = wx1*wy1;
                    #pragma unroll
                    for (int i = 0; i < 8; ++i) { float4 t = p[i];
                        s4[i].x += w*t.x; s4[i].y += w*t.y; s4[i].z += w*t.z; s4[i].w += w*t.w; }
                }
            }
        }

        if (did) {
            #pragma unroll
            for (int i = 0; i < 8; ++i) {
                float sv[4] = { s4[i].x, s4[i].y, s4[i].z, s4[i].w };
                #pragma unroll
                for (int j = 0; j < 4; ++j) {
                    float e = __expf(sv[j]);
                    A[4*i+j]  += e;
                    Bs[4*i+j] += sv[j]*e;
                }
            }
        } else {
            // sampled == 0 for this view: exp(0)=1 to denominator only
            #pragma unroll
            for (int c = 0; c < COUT; ++c) A[c] += 1.f;
        }
    }

    float* op = out + (size_t)b*COUT*NVOX + n;
    #pragma unroll
    for (int c = 0; c < COUT; ++c)
        op[(size_t)c*NVOX] = Bs[c] * __builtin_amdgcn_rcpf(A[c]);
}

extern "C" void kernel_launch(void* const* d_in, const int* in_sizes, int n_in,
                              void* d_out, int out_size, void* d_ws, size_t ws_size,
                              hipStream_t stream)
{
    const float* features = (const float*)d_in[0];   // [2,4,256,96,96]
    const float* proj     = (const float*)d_in[1];   // [2,4,3,4]
    const float* coords   = (const float*)d_in[2];   // [2,64,64,64,3]
    const float* Wp       = (const float*)d_in[3];   // [32,256]
    const float* bp       = (const float*)d_in[4];   // [32]
    float* out    = (float*)d_out;                   // [2,32,64,64,64]
    float* featsT = (float*)d_ws;                    // [2,4,96,96,32] = 9.44 MB

    hipLaunchKernelGGL(conv1x1_kernel, dim3(HW/256, NB*NV), dim3(256), 0, stream,
                       features, Wp, bp, featsT);
    hipLaunchKernelGGL(volgen_kernel, dim3(NVOX/256, NB), dim3(256), 0, stream,
                       featsT, proj, coords, out);
}

// Round 2
// 240.270 us; speedup vs baseline: 1.0197x; 1.0197x over previous
//
#include <hip/hip_runtime.h>

#define CIN   256
#define COUT  32
#define IMG_H 96
#define IMG_W 96
#define HW    (IMG_H*IMG_W)
#define NB    2
#define NV    4
#define VSZ   64
#define NVOX  (VSZ*VSZ*VSZ)

// Kernel 1: 1x1 conv -> channel-last [b,v,h,w,c].
// Block = 256 thr = 4 waves; wave og handles couts [og*8, og*8+8); each thread
// handles 4 consecutive pixels via float4 loads (32 indep FMA chains for ILP).
// The 4 waves read the same feature bytes -> L1-served, no extra HBM fetch.
__global__ __launch_bounds__(256) void conv1x1_kernel(
    const float* __restrict__ features,   // [B,V,CIN,H,W]
    const float* __restrict__ Wp,         // [COUT,CIN]
    const float* __restrict__ bp,         // [COUT]
    float* __restrict__ out)              // [B,V,H,W,COUT]
{
    __shared__ float Wt[CIN*COUT];        // [c][o], 32 KiB
    const int tid = threadIdx.x;
    #pragma unroll
    for (int i = 0; i < CIN*COUT/256; ++i) {
        int idx = i*256 + tid;
        int c = idx >> 5, o = idx & 31;
        Wt[idx] = Wp[o*CIN + c];
    }
    __syncthreads();

    const int og  = tid >> 6;             // wave index -> cout group
    const int pg  = tid & 63;             // pixel group (4 px each)
    const int bv  = blockIdx.y;
    const int px0 = blockIdx.x*256 + pg*4;
    const float* f = features + (size_t)bv*CIN*HW + px0;

    float acc[4][8];
    #pragma unroll
    for (int j = 0; j < 8; ++j) {
        float b = bp[og*8 + j];
        acc[0][j] = b; acc[1][j] = b; acc[2][j] = b; acc[3][j] = b;
    }

    #pragma unroll 8
    for (int c = 0; c < CIN; ++c) {
        const float4 x  = *(const float4*)(f + (size_t)c*HW);       // 16B/lane, coalesced
        const float4 w0 = *(const float4*)(&Wt[c*COUT + og*8]);     // wave-uniform -> broadcast
        const float4 w1 = *(const float4*)(&Wt[c*COUT + og*8 + 4]);
        const float xs[4] = {x.x, x.y, x.z, x.w};
        const float ws[8] = {w0.x,w0.y,w0.z,w0.w, w1.x,w1.y,w1.z,w1.w};
        #pragma unroll
        for (int p = 0; p < 4; ++p)
            #pragma unroll
            for (int j = 0; j < 8; ++j)
                acc[p][j] += xs[p]*ws[j];
    }

    #pragma unroll
    for (int p = 0; p < 4; ++p) {
        float4* op = (float4*)(out + ((size_t)(bv*HW + px0 + p))*COUT + og*8);
        op[0] = make_float4(acc[p][0], acc[p][1], acc[p][2], acc[p][3]);
        op[1] = make_float4(acc[p][4], acc[p][5], acc[p][6], acc[p][7]);
    }
}

// Kernel 2: 8 lanes cooperate per voxel (lane = channel float4 chunk).
// A corner gather = 8 lanes reading one contiguous, aligned 128B pixel record
// -> 8 cache lines per wave-instr instead of ~64. Streaming view-softmax.
// Output via padded LDS transpose for coalesced 128B store lines.
__global__ __launch_bounds__(256) void volgen_kernel(
    const float* __restrict__ feats,   // [B,V,H,W,COUT] channel-last
    const float* __restrict__ proj,    // [B,V,3,4]
    const float* __restrict__ coords,  // [B,NVOX,3]
    float* __restrict__ out)           // [B,COUT,NVOX]
{
    __shared__ float T[COUT*33];       // [ch][vox] +1-pad
    const int tid = threadIdx.x;
    const int vl  = tid >> 3;          // local voxel 0..31
    const int cg  = tid & 7;           // channel float4 group 0..7
    const int b   = blockIdx.y;
    const int n   = blockIdx.x*32 + vl;

    const float* cp = coords + ((size_t)b*NVOX + n)*3;
    const float X = cp[0], Y = cp[1], Z = cp[2];

    float A[4]  = {0.f,0.f,0.f,0.f};
    float Bs[4] = {0.f,0.f,0.f,0.f};

    #pragma unroll
    for (int v = 0; v < NV; ++v) {
        const float* P = proj + (size_t)(b*NV + v)*12;   // b,v uniform -> scalar loads
        const float wz = P[8]*X + P[9]*Y + P[10]*Z + P[11];
        float4 s = make_float4(0.f,0.f,0.f,0.f);
        bool did = false;

        if (wz > 0.f) {
            const float rz = __builtin_amdgcn_rcpf(wz);
            // px = u*(W-1)/H, py = v*(H-1)/W  (H==W==96)
            const float px = (P[0]*X + P[1]*Y + P[2]*Z + P[3]) * rz * (95.f/96.f);
            const float py = (P[4]*X + P[5]*Y + P[6]*Z + P[7]) * rz * (95.f/96.f);
            const float fx0 = floorf(px), fy0 = floorf(py);
            const int x0 = (int)fx0, y0 = (int)fy0, x1 = x0+1, y1 = y0+1;
            const bool vx0 = (x0 >= 0) & (x0 < IMG_W);
            const bool vx1 = (x1 >= 0) & (x1 < IMG_W);
            const bool vy0 = (y0 >= 0) & (y0 < IMG_H);
            const bool vy1 = (y1 >= 0) & (y1 < IMG_H);
            if ((vx0 | vx1) & (vy0 | vy1)) {
                did = true;
                const float wx1 = px - fx0, wx0 = 1.f - wx1;
                const float wy1 = py - fy0, wy0 = 1.f - wy1;
                const float* base = feats + ((size_t)(b*NV + v)*HW)*COUT + cg*4;
                if (vx0 & vy0) { const float4 t = *(const float4*)(base + (size_t)(y0*IMG_W + x0)*COUT);
                    const float w = wx0*wy0; s.x += w*t.x; s.y += w*t.y; s.z += w*t.z; s.w += w*t.w; }
                if (vx1 & vy0) { const float4 t = *(const float4*)(base + (size_t)(y0*IMG_W + x1)*COUT);
                    const float w = wx1*wy0; s.x += w*t.x; s.y += w*t.y; s.z += w*t.z; s.w += w*t.w; }
                if (vx0 & vy1) { const float4 t = *(const float4*)(base + (size_t)(y1*IMG_W + x0)*COUT);
                    const float w = wx0*wy1; s.x += w*t.x; s.y += w*t.y; s.z += w*t.z; s.w += w*t.w; }
                if (vx1 & vy1) { const float4 t = *(const float4*)(base + (size_t)(y1*IMG_W + x1)*COUT);
                    const float w = wx1*wy1; s.x += w*t.x; s.y += w*t.y; s.z += w*t.z; s.w += w*t.w; }
            }
        }

        if (did) {
            const float sv[4] = {s.x, s.y, s.z, s.w};
            #pragma unroll
            for (int j = 0; j < 4; ++j) {
                const float e = __expf(sv[j]);
                A[j] += e; Bs[j] += sv[j]*e;
            }
        } else {
            #pragma unroll
            for (int j = 0; j < 4; ++j) A[j] += 1.f;   // exp(0) to denominator
        }
    }

    #pragma unroll
    for (int j = 0; j < 4; ++j)
        T[(cg*4 + j)*33 + vl] = Bs[j] * __builtin_amdgcn_rcpf(A[j]);
    __syncthreads();

    const size_t ob = (size_t)b*COUT*NVOX + (size_t)blockIdx.x*32;
    #pragma unroll
    for (int i = 0; i < 4; ++i) {
        const int idx = i*256 + tid;
        const int ch = idx >> 5, vx = idx & 31;
        out[ob + (size_t)ch*NVOX + vx] = T[ch*33 + vx];
    }
}

extern "C" void kernel_launch(void* const* d_in, const int* in_sizes, int n_in,
                              void* d_out, int out_size, void* d_ws, size_t ws_size,
                              hipStream_t stream)
{
    const float* features = (const float*)d_in[0];   // [2,4,256,96,96]
    const float* proj     = (const float*)d_in[1];   // [2,4,3,4]
    const float* coords   = (const float*)d_in[2];   // [2,64,64,64,3]
    const float* Wp       = (const float*)d_in[3];   // [32,256]
    const float* bp       = (const float*)d_in[4];   // [32]
    float* out    = (float*)d_out;                   // [2,32,64,64,64]
    float* featsT = (float*)d_ws;                    // [2,4,96,96,32] = 9.44 MB

    hipLaunchKernelGGL(conv1x1_kernel, dim3(HW/256, NB*NV), dim3(256), 0, stream,
                       features, Wp, bp, featsT);
    hipLaunchKernelGGL(volgen_kernel, dim3(NVOX/32, NB), dim3(256), 0, stream,
                       featsT, proj, coords, out);
}

// Round 3
// 211.219 us; speedup vs baseline: 1.1600x; 1.1375x over previous
//
#include <hip/hip_runtime.h>
#include <hip/hip_bf16.h>

#define CIN   256
#define COUT  32
#define IMG_H 96
#define IMG_W 96
#define HW    (IMG_H*IMG_W)
#define NB    2
#define NV    4
#define VSZ   64
#define NVOX  (VSZ*VSZ*VSZ)

// Kernel 1: 1x1 conv -> channel-last bf16 [b,v,h,w,c].
// Block = 256 thr = 4 waves. Wave og owns couts [og*8, og*8+8); lane owns 1 px.
// Block covers 64 px; grid = (9216/64=144, 8) = 1152 blocks -> ~4.5 blocks/CU
// (vs 288 blocks / 11% occupancy in R2 -- the latency-hiding fix).
__global__ __launch_bounds__(256) void conv1x1_kernel(
    const float* __restrict__ features,   // [B,V,CIN,H,W] fp32
    const float* __restrict__ Wp,         // [COUT,CIN]
    const float* __restrict__ bp,         // [COUT]
    __hip_bfloat16* __restrict__ out)     // [B,V,H,W,COUT] bf16
{
    __shared__ float Wt[CIN*COUT];        // [c][o], 32 KiB
    const int tid = threadIdx.x;
    #pragma unroll
    for (int i = 0; i < CIN*COUT/256; ++i) {
        int idx = i*256 + tid;
        int c = idx >> 5, o = idx & 31;
        Wt[idx] = Wp[o*CIN + c];
    }
    __syncthreads();

    const int og   = tid >> 6;            // wave -> cout group (wave-uniform)
    const int lane = tid & 63;
    const int bv   = blockIdx.y;
    const int px   = blockIdx.x*64 + lane;
    const float* f = features + (size_t)bv*CIN*HW + px;

    float acc[8];
    #pragma unroll
    for (int j = 0; j < 8; ++j) acc[j] = bp[og*8 + j];

    #pragma unroll 8
    for (int c = 0; c < CIN; ++c) {
        const float x = f[(size_t)c*HW];                        // 256B/wave, coalesced
        const float4 w0 = *(const float4*)(&Wt[c*COUT + og*8]); // broadcast b128
        const float4 w1 = *(const float4*)(&Wt[c*COUT + og*8 + 4]);
        acc[0] += x*w0.x; acc[1] += x*w0.y; acc[2] += x*w0.z; acc[3] += x*w0.w;
        acc[4] += x*w1.x; acc[5] += x*w1.y; acc[6] += x*w1.z; acc[7] += x*w1.w;
    }

    union { uint4 u4; __hip_bfloat16 h[8]; } pk;
    #pragma unroll
    for (int j = 0; j < 8; ++j) pk.h[j] = __float2bfloat16(acc[j]);
    *(uint4*)(out + ((size_t)(bv*HW + px))*COUT + og*8) = pk.u4;
}

// Kernel 2: 4 lanes per voxel; lane owns 8 channels (16 B = uint4 of bf16x8).
// One corner-gather instr = 16 voxels x one 64B pixel line. Streaming
// view-softmax; padded-LDS transpose for coalesced fp32 output.
__global__ __launch_bounds__(256) void volgen_kernel(
    const __hip_bfloat16* __restrict__ feats,  // [B,V,H,W,COUT] bf16
    const float* __restrict__ proj,            // [B,V,3,4]
    const float* __restrict__ coords,          // [B,NVOX,3]
    float* __restrict__ out)                   // [B,COUT,NVOX]
{
    __shared__ float T[COUT*65];               // [ch][vox] +1 pad, 33.3 KiB
    const int tid = threadIdx.x;
    const int vl  = tid >> 2;                  // local voxel 0..63
    const int cg  = tid & 3;                   // channel oct 0..3 (8 ch each)
    const int b   = blockIdx.y;
    const int n   = blockIdx.x*64 + vl;

    const float* cp = coords + ((size_t)b*NVOX + n)*3;
    const float X = cp[0], Y = cp[1], Z = cp[2];

    float A[8], Bs[8];
    #pragma unroll
    for (int j = 0; j < 8; ++j) { A[j] = 0.f; Bs[j] = 0.f; }

    #pragma unroll
    for (int v = 0; v < NV; ++v) {
        const float* P = proj + (size_t)(b*NV + v)*12;   // uniform -> scalar loads
        const float wz = P[8]*X + P[9]*Y + P[10]*Z + P[11];
        float s[8];
        #pragma unroll
        for (int j = 0; j < 8; ++j) s[j] = 0.f;
        bool did = false;

        if (wz > 0.f) {
            const float rz = __builtin_amdgcn_rcpf(wz);
            // px = u*(W-1)/H, py = v*(H-1)/W  (H==W==96)
            const float px = (P[0]*X + P[1]*Y + P[2]*Z + P[3]) * rz * (95.f/96.f);
            const float py = (P[4]*X + P[5]*Y + P[6]*Z + P[7]) * rz * (95.f/96.f);
            const float fx0 = floorf(px), fy0 = floorf(py);
            const int x0 = (int)fx0, y0 = (int)fy0, x1 = x0+1, y1 = y0+1;
            const bool vx0 = (x0 >= 0) & (x0 < IMG_W);
            const bool vx1 = (x1 >= 0) & (x1 < IMG_W);
            const bool vy0 = (y0 >= 0) & (y0 < IMG_H);
            const bool vy1 = (y1 >= 0) & (y1 < IMG_H);
            if ((vx0 | vx1) & (vy0 | vy1)) {
                did = true;
                const float wx1 = px - fx0, wx0 = 1.f - wx1;
                const float wy1 = py - fy0, wy0 = 1.f - wy1;
                const __hip_bfloat16* base =
                    feats + ((size_t)(b*NV + v)*HW)*COUT + cg*8;
                #pragma unroll
                for (int corner = 0; corner < 4; ++corner) {
                    const int cx = (corner & 1) ? x1 : x0;
                    const int cy = (corner & 2) ? y1 : y0;
                    const bool ok = ((corner & 1) ? vx1 : vx0) &
                                    ((corner & 2) ? vy1 : vy0);
                    if (ok) {
                        const float w = ((corner & 1) ? wx1 : wx0) *
                                        ((corner & 2) ? wy1 : wy0);
                        const uint4 t = *(const uint4*)(base + (size_t)(cy*IMG_W + cx)*COUT);
                        const unsigned tu[4] = { t.x, t.y, t.z, t.w };
                        #pragma unroll
                        for (int k = 0; k < 4; ++k) {
                            s[2*k]   += w * __uint_as_float(tu[k] << 16);
                            s[2*k+1] += w * __uint_as_float(tu[k] & 0xffff0000u);
                        }
                    }
                }
            }
        }

        if (did) {
            #pragma unroll
            for (int j = 0; j < 8; ++j) {
                const float e = __expf(s[j]);
                A[j] += e; Bs[j] += s[j]*e;
            }
        } else {
            #pragma unroll
            for (int j = 0; j < 8; ++j) A[j] += 1.f;   // exp(0) -> denominator
        }
    }

    #pragma unroll
    for (int j = 0; j < 8; ++j)
        T[(cg*8 + j)*65 + vl] = Bs[j] * __builtin_amdgcn_rcpf(A[j]);
    __syncthreads();

    const size_t ob = (size_t)b*COUT*NVOX + (size_t)blockIdx.x*64;
    #pragma unroll
    for (int i = 0; i < 8; ++i) {
        const int idx = i*256 + tid;
        const int ch = idx >> 6, vx = idx & 63;
        out[ob + (size_t)ch*NVOX + vx] = T[ch*65 + vx];
    }
}

extern "C" void kernel_launch(void* const* d_in, const int* in_sizes, int n_in,
                              void* d_out, int out_size, void* d_ws, size_t ws_size,
                              hipStream_t stream)
{
    const float* features = (const float*)d_in[0];   // [2,4,256,96,96]
    const float* proj     = (const float*)d_in[1];   // [2,4,3,4]
    const float* coords   = (const float*)d_in[2];   // [2,64,64,64,3]
    const float* Wp       = (const float*)d_in[3];   // [32,256]
    const float* bp       = (const float*)d_in[4];   // [32]
    float* out = (float*)d_out;                      // [2,32,64,64,64]
    __hip_bfloat16* featsT = (__hip_bfloat16*)d_ws;  // [2,4,96,96,32] bf16 = 4.72 MB

    hipLaunchKernelGGL(conv1x1_kernel, dim3(HW/64, NB*NV), dim3(256), 0, stream,
                       features, Wp, bp, featsT);
    hipLaunchKernelGGL(volgen_kernel, dim3(NVOX/64, NB), dim3(256), 0, stream,
                       featsT, proj, coords, out);
}